// Round 2
// baseline (932.749 us; speedup 1.0000x reference)
//
#include <hip/hip_runtime.h>
#include <cmath>

#define NNODES 20000
#define NEDGES 320000

// LDS per-node stride (floats): 576 data + 4 pad so node n starts at bank 4n%32.
#define VSTR  580
#define VSTR4 145   // in float4s

// ---------------------------------------------------------------------------
// Edge kernel: per-edge RBF * envelope, scatter-add (env*phi[32], env) per node.
// ---------------------------------------------------------------------------
__global__ __launch_bounds__(256) void edge_kernel(
    const float* __restrict__ dist, const int* __restrict__ nb,
    float* __restrict__ Phi, float* __restrict__ Env,
    float mu0, float mustep, float beta)
{
    int e = blockIdx.x * 256 + threadIdx.x;
    if (e >= NEDGES) return;
    float d = dist[e];
    int   n = nb[e];
    float ed  = expf(-d);
    float env = (d < 5.0f) ? 0.5f * (cosf(0.62831853071795864769f * d) + 1.0f) : 0.0f;
    float* prow = Phi + (size_t)n * 32;
#pragma unroll
    for (int r = 0; r < 32; ++r) {
        float mu = mu0 + (float)r * mustep;
        float t  = ed - mu;
        atomicAdd(prow + r, env * expf(-beta * t * t));
    }
    atomicAdd(Env + n, env);
}

// ---------------------------------------------------------------------------
// mix4: irrep-space channel mixing for outputs o_j = q + 16j, j=0..3.
// vbase = LDS [comp(9)][chan(64)] for this node (node stride VSTR).
// comps: [0]=iso, [1..3]=A(a01,a02,a12), [4..8]=S(s00,s01,s02,s11,s12)
// ---------------------------------------------------------------------------
__device__ __forceinline__ void mix4(const float* __restrict__ vbase,
    const float* __restrict__ WI, const float* __restrict__ WA,
    const float* __restrict__ WS, int q, float (&y)[4][9])
{
#pragma unroll
    for (int j = 0; j < 4; ++j)
#pragma unroll
        for (int k = 0; k < 9; ++k) y[j][k] = 0.f;

#pragma unroll 2
    for (int c4 = 0; c4 < 16; ++c4) {
        float v[9][4];
#pragma unroll
        for (int k = 0; k < 9; ++k) {
            float4 t = *reinterpret_cast<const float4*>(vbase + k * 64 + c4 * 4);
            v[k][0] = t.x; v[k][1] = t.y; v[k][2] = t.z; v[k][3] = t.w;
        }
#pragma unroll
        for (int j = 0; j < 4; ++j) {
            const int o = q + 16 * j;
            float a[4], b[4], c[4];
            { float4 t = reinterpret_cast<const float4*>(WI + o * 64)[c4]; a[0]=t.x; a[1]=t.y; a[2]=t.z; a[3]=t.w; }
            { float4 t = reinterpret_cast<const float4*>(WA + o * 64)[c4]; b[0]=t.x; b[1]=t.y; b[2]=t.z; b[3]=t.w; }
            { float4 t = reinterpret_cast<const float4*>(WS + o * 64)[c4]; c[0]=t.x; c[1]=t.y; c[2]=t.z; c[3]=t.w; }
#pragma unroll
            for (int jj = 0; jj < 4; ++jj) {
                y[j][0] += a[jj] * v[0][jj];
                y[j][1] += b[jj] * v[1][jj];
                y[j][2] += b[jj] * v[2][jj];
                y[j][3] += b[jj] * v[3][jj];
                y[j][4] += c[jj] * v[4][jj];
                y[j][5] += c[jj] * v[5][jj];
                y[j][6] += c[jj] * v[6][jj];
                y[j][7] += c[jj] * v[7][jj];
                y[j][8] += c[jj] * v[8][jj];
            }
        }
    }
}

// ---------------------------------------------------------------------------
// Node kernel: 16 nodes / 256-thread block, 16 threads per node,
// each thread owns channels {q, q+16, q+32, q+48}.
// ---------------------------------------------------------------------------
__global__ __launch_bounds__(256) void node_kernel(
    const float* __restrict__ X,
    const float* __restrict__ Phi, const float* __restrict__ Env,
    const float* __restrict__ WIpre,  const float* __restrict__ WApre,  const float* __restrict__ WSpre,
    const float* __restrict__ WIpost, const float* __restrict__ WApost, const float* __restrict__ WSpost,
    const float* __restrict__ Wdist, const float* __restrict__ bdist,
    float* __restrict__ out)
{
    __shared__ __align__(16) float vals[16 * VSTR];   // raw X / comps / out (aliased)
    __shared__ __align__(16) float phiS[16 * 36];     // padded rows: bank spread
    __shared__ float envS[16];

    const int tid = threadIdx.x;
    const int ln  = tid >> 4;          // node in block (0..15)
    const int q   = tid & 15;          // lane within node group
    const int node0 = blockIdx.x * 16;
    float* vb = &vals[ln * VSTR];

    // ---- cooperative load of X tile (contiguous per node, stride VSTR4) ----
    {
        const float4* src = reinterpret_cast<const float4*>(X + (size_t)node0 * 576);
        float4* dst = reinterpret_cast<float4*>(vals);
        for (int i = tid; i < 2304; i += 256) dst[(i / 144) * VSTR4 + (i % 144)] = src[i];
    }
    for (int i = tid; i < 512; i += 256)
        phiS[(i >> 5) * 36 + (i & 31)] = Phi[(size_t)(node0 + (i >> 5)) * 32 + (i & 31)];
    if (tid < 16) envS[tid] = Env[node0 + tid];
    __syncthreads();

    // ---- normalize + decompose (4 channels / thread), raw read -> regs ----
    float comps[4][9];
#pragma unroll
    for (int h = 0; h < 4; ++h) {
        const int c = q + 16 * h;
        const float* x = vb + c * 9;
        float v[9];
#pragma unroll
        for (int k = 0; k < 9; ++k) v[k] = x[k];
        float fr = 0.f;
#pragma unroll
        for (int k = 0; k < 9; ++k) fr += v[k] * v[k];
        float s = 1.0f / (fr + 1.0f);
#pragma unroll
        for (int k = 0; k < 9; ++k) v[k] *= s;
        float dm = (v[0] + v[4] + v[8]) * (1.0f / 3.0f);
        comps[h][0] = dm;
        comps[h][1] = 0.5f * (v[1] - v[3]);
        comps[h][2] = 0.5f * (v[2] - v[6]);
        comps[h][3] = 0.5f * (v[5] - v[7]);
        comps[h][4] = v[0] - dm;
        comps[h][5] = 0.5f * (v[1] + v[3]);
        comps[h][6] = 0.5f * (v[2] + v[6]);
        comps[h][7] = v[4] - dm;
        comps[h][8] = 0.5f * (v[5] + v[7]);
    }
    __syncthreads();   // all raw reads done before overwriting with comps
#pragma unroll
    for (int h = 0; h < 4; ++h) {
        const int c = q + 16 * h;
#pragma unroll
        for (int k = 0; k < 9; ++k) vb[k * 64 + c] = comps[h][k];
    }
    __syncthreads();

    // ---- pre mixing ----
    float y[4][9];
    mix4(vb, WIpre, WApre, WSpre, q, y);

    // ---- edge coefficient sums for this node's channels ----
    float fIv[4], fAv[4], fSv[4];
    {
        const float4* ph = reinterpret_cast<const float4*>(&phiS[ln * 36]);
        float es = envS[ln];
#pragma unroll
        for (int h = 0; h < 4; ++h) {
            const int c = q + 16 * h;
            float accI = 0.f, accA = 0.f, accS = 0.f;
            const float4* wI = reinterpret_cast<const float4*>(Wdist + (size_t)c * 32);
            const float4* wA = reinterpret_cast<const float4*>(Wdist + (size_t)(64 + c) * 32);
            const float4* wS = reinterpret_cast<const float4*>(Wdist + (size_t)(128 + c) * 32);
#pragma unroll
            for (int r = 0; r < 8; ++r) {
                float4 p = ph[r];
                float4 a = wI[r]; accI += p.x*a.x + p.y*a.y + p.z*a.z + p.w*a.w;
                float4 b = wA[r]; accA += p.x*b.x + p.y*b.y + p.z*b.z + p.w*b.w;
                float4 cc= wS[r]; accS += p.x*cc.x + p.y*cc.y + p.z*cc.z + p.w*cc.w;
            }
            fIv[h] = accI + es * bdist[c];
            fAv[h] = accA + es * bdist[64 + c];
            fSv[h] = accS + es * bdist[128 + c];
        }
    }

    // ---- per-channel tensor algebra ----
    float yn2[4][9];
#pragma unroll
    for (int h = 0; h < 4; ++h) {
        const int c = q + 16 * h;
        float cc[9];
#pragma unroll
        for (int k = 0; k < 9; ++k) cc[k] = vb[k * 64 + c];
        float fi = fIv[h], fa = fAv[h], fs = fSv[h];
        float m[9];
        m[0] =  fi * cc[0] + fs * cc[4];
        m[1] =  fa * cc[1] + fs * cc[5];
        m[2] =  fa * cc[2] + fs * cc[6];
        m[3] = -fa * cc[1] + fs * cc[5];
        m[4] =  fi * cc[0] + fs * cc[7];
        m[5] =  fa * cc[3] + fs * cc[8];
        m[6] = -fa * cc[2] + fs * cc[6];
        m[7] = -fa * cc[3] + fs * cc[8];
        m[8] =  fi * cc[0] - fs * (cc[4] + cc[7]);
        float yf[9];
        yf[0] =  y[h][0] + y[h][4];
        yf[1] =  y[h][1] + y[h][5];
        yf[2] =  y[h][2] + y[h][6];
        yf[3] = -y[h][1] + y[h][5];
        yf[4] =  y[h][0] + y[h][7];
        yf[5] =  y[h][3] + y[h][8];
        yf[6] = -y[h][2] + y[h][6];
        yf[7] = -y[h][3] + y[h][8];
        yf[8] =  y[h][0] - y[h][4] - y[h][7];
        float t[9];
#pragma unroll
        for (int i = 0; i < 3; ++i)
#pragma unroll
            for (int j = 0; j < 3; ++j) {
                float acc = 0.f;
#pragma unroll
                for (int k = 0; k < 3; ++k)
                    acc += yf[i*3+k] * m[k*3+j] + m[i*3+k] * yf[k*3+j];
                t[i*3+j] = acc;
            }
        float nr = 0.f;
#pragma unroll
        for (int k = 0; k < 9; ++k) { float u = t[k] + 1.0f; nr += u * u; }
        float inv = 1.0f / nr;
#pragma unroll
        for (int k = 0; k < 9; ++k) t[k] *= inv;
        float dm = (t[0] + t[4] + t[8]) * (1.0f / 3.0f);
        yn2[h][0] = dm;
        yn2[h][1] = 0.5f * (t[1] - t[3]);
        yn2[h][2] = 0.5f * (t[2] - t[6]);
        yn2[h][3] = 0.5f * (t[5] - t[7]);
        yn2[h][4] = t[0] - dm;
        yn2[h][5] = 0.5f * (t[1] + t[3]);
        yn2[h][6] = 0.5f * (t[2] + t[6]);
        yn2[h][7] = t[4] - dm;
        yn2[h][8] = 0.5f * (t[5] + t[7]);
    }
    __syncthreads();   // everyone done reading stage-1 comps
#pragma unroll
    for (int h = 0; h < 4; ++h) {
        const int c = q + 16 * h;
#pragma unroll
        for (int k = 0; k < 9; ++k) vb[k * 64 + c] = yn2[h][k];
    }
    __syncthreads();

    // ---- post mixing ----
    float z[4][9];
    mix4(vb, WIpost, WApost, WSpost, q, z);
    __syncthreads();   // everyone done reading stage-2 comps

    // ---- reconstruct, out = Y + Y@Y, stage contiguous per node ----
#pragma unroll
    for (int h = 0; h < 4; ++h) {
        const int o = q + 16 * h;
        float w[9];
        w[0] =  z[h][0] + z[h][4];
        w[1] =  z[h][1] + z[h][5];
        w[2] =  z[h][2] + z[h][6];
        w[3] = -z[h][1] + z[h][5];
        w[4] =  z[h][0] + z[h][7];
        w[5] =  z[h][3] + z[h][8];
        w[6] = -z[h][2] + z[h][6];
        w[7] = -z[h][3] + z[h][8];
        w[8] =  z[h][0] - z[h][4] - z[h][7];
#pragma unroll
        for (int i = 0; i < 3; ++i)
#pragma unroll
            for (int j = 0; j < 3; ++j) {
                float acc = w[i*3+j];
#pragma unroll
                for (int k = 0; k < 3; ++k) acc += w[i*3+k] * w[k*3+j];
                vb[o * 9 + i*3+j] = acc;
            }
    }
    __syncthreads();
    {
        float4* dst = reinterpret_cast<float4*>(out + (size_t)node0 * 576);
        const float4* srcv = reinterpret_cast<const float4*>(vals);
        for (int i = tid; i < 2304; i += 256) dst[i] = srcv[(i / 144) * VSTR4 + (i % 144)];
    }
}

// ---------------------------------------------------------------------------
extern "C" void kernel_launch(void* const* d_in, const int* in_sizes, int n_in,
                              void* d_out, int out_size, void* d_ws, size_t ws_size,
                              hipStream_t stream)
{
    const float* X      = (const float*)d_in[0];
    const float* dist   = (const float*)d_in[1];
    const int*   nb     = (const int*)d_in[2];
    const float* WIpre  = (const float*)d_in[3];
    const float* WApre  = (const float*)d_in[4];
    const float* WSpre  = (const float*)d_in[5];
    const float* WIpost = (const float*)d_in[6];
    const float* WApost = (const float*)d_in[7];
    const float* WSpost = (const float*)d_in[8];
    const float* Wdist  = (const float*)d_in[9];
    const float* bdist  = (const float*)d_in[10];
    float* out = (float*)d_out;

    float* Phi = (float*)d_ws;                  // NNODES*32 floats (env-weighted RBF sums)
    float* Env = Phi + (size_t)NNODES * 32;     // NNODES floats (env sums)

    hipMemsetAsync(d_ws, 0, ((size_t)NNODES * 32 + NNODES) * sizeof(float), stream);

    double em5   = std::exp(-5.0);
    double step  = (1.0 - em5) / 31.0;
    double fac   = (2.0 / 32.0) * (1.0 - em5);
    double betad = 1.0 / (fac * fac);

    edge_kernel<<<(NEDGES + 255) / 256, 256, 0, stream>>>(
        dist, nb, Phi, Env, (float)em5, (float)step, (float)betad);
    node_kernel<<<NNODES / 16, 256, 0, stream>>>(
        X, Phi, Env, WIpre, WApre, WSpre, WIpost, WApost, WSpost, Wdist, bdist, out);
}

// Round 5
// 546.827 us; speedup vs baseline: 1.7057x; 1.7057x over previous
//
#include <hip/hip_runtime.h>
#include <cmath>

#define NNODES 20000
#define NEDGES 320000

// LDS per-node stride (floats): 576 data + 8 pad -> node ln starts at bank 8*ln%32.
#define VSTR  584
#define VSTR4 146   // in float4s
#define WSTRIDE 68  // LDS weight row stride (floats): bank advance 4 per row

// ===========================================================================
// Edge path: CSR build (2 atomics/edge) + gather (0 atomics)
// ===========================================================================
__global__ __launch_bounds__(256) void hist_kernel(
    const int* __restrict__ nb, int* __restrict__ counts)
{
    int e = blockIdx.x * 256 + threadIdx.x;
    if (e >= NEDGES) return;
    atomicAdd(counts + nb[e], 1);
}

__global__ __launch_bounds__(1024) void scan_kernel(
    const int* __restrict__ counts, int* __restrict__ base)
{
    __shared__ int part[1024];
    const int t = threadIdx.x;
    int loc[20];
    int s = 0;
#pragma unroll
    for (int j = 0; j < 20; ++j) {
        int idx = t * 20 + j;
        int v = (idx < NNODES) ? counts[idx] : 0;
        loc[j] = s;
        s += v;
    }
    part[t] = s;
    __syncthreads();
    for (int off = 1; off < 1024; off <<= 1) {
        int v = (t >= off) ? part[t - off] : 0;
        __syncthreads();
        part[t] += v;
        __syncthreads();
    }
    int excl = (t > 0) ? part[t - 1] : 0;
#pragma unroll
    for (int j = 0; j < 20; ++j) {
        int idx = t * 20 + j;
        if (idx < NNODES) base[idx] = excl + loc[j];
    }
}

__global__ __launch_bounds__(256) void fill_kernel(
    const float* __restrict__ dist, const int* __restrict__ nb,
    const int* __restrict__ base, int* __restrict__ cursor,
    float* __restrict__ sorted_d)
{
    int e = blockIdx.x * 256 + threadIdx.x;
    if (e >= NEDGES) return;
    int n = nb[e];
    int slot = base[n] + atomicAdd(cursor + n, 1);
    sorted_d[slot] = dist[e];
}

// Per node: phi[32] = sum_e env*rbf, es = sum_e env. No atomics.
// 64-thread blocks: 313 blocks spread across all 256 CUs (latency-bound dispatch).
__global__ __launch_bounds__(64) void node_phi_kernel(
    const float* __restrict__ sorted_d, const int* __restrict__ base,
    const int* __restrict__ counts,
    float* __restrict__ Phi, float* __restrict__ Env,
    float mu0, float mustep, float beta)
{
    int n = blockIdx.x * 64 + threadIdx.x;
    if (n >= NNODES) return;
    int st = base[n], cnt = counts[n];
    float phi[32];
#pragma unroll
    for (int r = 0; r < 32; ++r) phi[r] = 0.f;
    float es = 0.f;
    for (int j = 0; j < cnt; ++j) {
        float d = sorted_d[st + j];
        float ed = expf(-d);
        float env = (d < 5.0f) ? 0.5f * (cosf(0.62831853071795864769f * d) + 1.0f) : 0.0f;
        es += env;
#pragma unroll
        for (int r = 0; r < 32; ++r) {
            float t = ed - (mu0 + (float)r * mustep);
            phi[r] += env * expf(-beta * t * t);
        }
    }
#pragma unroll
    for (int r = 0; r < 32; ++r) Phi[(size_t)n * 32 + r] = phi[r];
    Env[n] = es;
}

// ===========================================================================
// Node kernel: 16 nodes / 256-thread block, 16 threads/node, 4 out-chans each.
// Weight matrices staged ONE AT A TIME in LDS (rows padded to stride 68).
// ===========================================================================
__device__ __forceinline__ void stage_w(const float* __restrict__ W,
                                        float* __restrict__ wbuf, int tid)
{
#pragma unroll
    for (int i = 0; i < 4; ++i) {
        int idx = tid + i * 256;         // float4 id 0..1023
        int row = idx >> 4;              // 16 float4 per 64-float row
        int seg = idx & 15;
        float4 t = reinterpret_cast<const float4*>(W)[idx];
        *reinterpret_cast<float4*>(wbuf + row * WSTRIDE + seg * 4) = t;
    }
}

// y[j][K0+kk] += sum_c wbuf[(q+16j)*68+c] * vb[(K0+kk)*64+c]
template <int K0, int NK>
__device__ __forceinline__ void mix_phase(const float* __restrict__ vb,
    const float* __restrict__ wbuf, int q, float (&y)[4][9])
{
#pragma unroll
    for (int c4 = 0; c4 < 16; ++c4) {
        float4 v[NK];
#pragma unroll
        for (int kk = 0; kk < NK; ++kk)
            v[kk] = *reinterpret_cast<const float4*>(vb + (K0 + kk) * 64 + c4 * 4);
#pragma unroll
        for (int j = 0; j < 4; ++j) {
            float4 w = *reinterpret_cast<const float4*>(wbuf + (q + 16 * j) * WSTRIDE + c4 * 4);
#pragma unroll
            for (int kk = 0; kk < NK; ++kk)
                y[j][K0 + kk] += w.x * v[kk].x + w.y * v[kk].y + w.z * v[kk].z + w.w * v[kk].w;
        }
    }
}

__global__ __launch_bounds__(256) void node_kernel(
    const float* __restrict__ X,
    const float* __restrict__ Phi, const float* __restrict__ Env,
    const float* __restrict__ WIpre,  const float* __restrict__ WApre,  const float* __restrict__ WSpre,
    const float* __restrict__ WIpost, const float* __restrict__ WApost, const float* __restrict__ WSpost,
    const float* __restrict__ Wdist, const float* __restrict__ bdist,
    float* __restrict__ out)
{
    __shared__ __align__(16) float vals[16 * VSTR];     // 37.4 KB
    __shared__ __align__(16) float wbuf[64 * WSTRIDE];  // 17.4 KB
    __shared__ __align__(16) float phiS[16 * 36];       // 2.3 KB
    __shared__ float envS[16];

    const int tid = threadIdx.x;
    const int ln  = tid >> 4;          // node in block (0..15)
    const int q   = tid & 15;          // lane in node group
    const int node0 = blockIdx.x * 16;
    float* vb = &vals[ln * VSTR];

    // ---- loads: X tile, phi, env; stage pre-iso weights ----
    {
        const float4* src = reinterpret_cast<const float4*>(X + (size_t)node0 * 576);
        float4* dst = reinterpret_cast<float4*>(vals);
        for (int i = tid; i < 2304; i += 256) dst[(i / 144) * VSTR4 + (i % 144)] = src[i];
    }
    for (int i = tid; i < 512; i += 256)
        phiS[(i >> 5) * 36 + (i & 31)] = Phi[(size_t)(node0 + (i >> 5)) * 32 + (i & 31)];
    if (tid < 16) envS[tid] = Env[node0 + tid];
    stage_w(WIpre, wbuf, tid);
    __syncthreads();                                    // (1)

    // ---- normalize + decompose (4 channels/thread) ----
    float comps[4][9];
#pragma unroll
    for (int h = 0; h < 4; ++h) {
        const int c = q + 16 * h;
        const float* x = vb + c * 9;
        float v[9];
#pragma unroll
        for (int k = 0; k < 9; ++k) v[k] = x[k];
        float fr = 0.f;
#pragma unroll
        for (int k = 0; k < 9; ++k) fr += v[k] * v[k];
        float s = 1.0f / (fr + 1.0f);
#pragma unroll
        for (int k = 0; k < 9; ++k) v[k] *= s;
        float dm = (v[0] + v[4] + v[8]) * (1.0f / 3.0f);
        comps[h][0] = dm;
        comps[h][1] = 0.5f * (v[1] - v[3]);
        comps[h][2] = 0.5f * (v[2] - v[6]);
        comps[h][3] = 0.5f * (v[5] - v[7]);
        comps[h][4] = v[0] - dm;
        comps[h][5] = 0.5f * (v[1] + v[3]);
        comps[h][6] = 0.5f * (v[2] + v[6]);
        comps[h][7] = v[4] - dm;
        comps[h][8] = 0.5f * (v[5] + v[7]);
    }
    __syncthreads();                                    // (2) raw reads done
#pragma unroll
    for (int h = 0; h < 4; ++h) {
        const int c = q + 16 * h;
#pragma unroll
        for (int k = 0; k < 9; ++k) vb[k * 64 + c] = comps[h][k];
    }
    __syncthreads();                                    // (3) comps visible

    // ---- edge coefficient sums (phiS LDS + Wdist via L1) ----
    float fIv[4], fAv[4], fSv[4];
    {
        float4 p[8];
        const float4* ph = reinterpret_cast<const float4*>(&phiS[ln * 36]);
#pragma unroll
        for (int r = 0; r < 8; ++r) p[r] = ph[r];
        float es = envS[ln];
#pragma unroll
        for (int h = 0; h < 4; ++h) {
            const int c = q + 16 * h;
            float accI = 0.f, accA = 0.f, accS = 0.f;
            const float4* wI = reinterpret_cast<const float4*>(Wdist + (size_t)c * 32);
            const float4* wA = reinterpret_cast<const float4*>(Wdist + (size_t)(64 + c) * 32);
            const float4* wS = reinterpret_cast<const float4*>(Wdist + (size_t)(128 + c) * 32);
#pragma unroll
            for (int r = 0; r < 8; ++r) {
                float4 a = wI[r]; accI += p[r].x*a.x + p[r].y*a.y + p[r].z*a.z + p[r].w*a.w;
                float4 b = wA[r]; accA += p[r].x*b.x + p[r].y*b.y + p[r].z*b.z + p[r].w*b.w;
                float4 cc= wS[r]; accS += p[r].x*cc.x + p[r].y*cc.y + p[r].z*cc.z + p[r].w*cc.w;
            }
            fIv[h] = accI + es * bdist[c];
            fAv[h] = accA + es * bdist[64 + c];
            fSv[h] = accS + es * bdist[128 + c];
        }
    }

    // ---- pre mixing: I, A, S sub-phases with one LDS-staged matrix each ----
    float y[4][9];
#pragma unroll
    for (int j = 0; j < 4; ++j)
#pragma unroll
        for (int k = 0; k < 9; ++k) y[j][k] = 0.f;

    mix_phase<0, 1>(vb, wbuf, q, y);
    __syncthreads();                                    // (4) done reading WIpre
    stage_w(WApre, wbuf, tid);
    __syncthreads();                                    // (5)
    mix_phase<1, 3>(vb, wbuf, q, y);
    __syncthreads();                                    // (6)
    stage_w(WSpre, wbuf, tid);
    __syncthreads();                                    // (7)
    mix_phase<4, 5>(vb, wbuf, q, y);

    // ---- per-channel tensor algebra (reads comps, still intact) ----
    float yn2[4][9];
#pragma unroll
    for (int h = 0; h < 4; ++h) {
        const int c = q + 16 * h;
        float cc[9];
#pragma unroll
        for (int k = 0; k < 9; ++k) cc[k] = vb[k * 64 + c];
        float fi = fIv[h], fa = fAv[h], fs = fSv[h];
        float m[9];
        m[0] =  fi * cc[0] + fs * cc[4];
        m[1] =  fa * cc[1] + fs * cc[5];
        m[2] =  fa * cc[2] + fs * cc[6];
        m[3] = -fa * cc[1] + fs * cc[5];
        m[4] =  fi * cc[0] + fs * cc[7];
        m[5] =  fa * cc[3] + fs * cc[8];
        m[6] = -fa * cc[2] + fs * cc[6];
        m[7] = -fa * cc[3] + fs * cc[8];
        m[8] =  fi * cc[0] - fs * (cc[4] + cc[7]);
        float yf[9];
        yf[0] =  y[h][0] + y[h][4];
        yf[1] =  y[h][1] + y[h][5];
        yf[2] =  y[h][2] + y[h][6];
        yf[3] = -y[h][1] + y[h][5];
        yf[4] =  y[h][0] + y[h][7];
        yf[5] =  y[h][3] + y[h][8];
        yf[6] = -y[h][2] + y[h][6];
        yf[7] = -y[h][3] + y[h][8];
        yf[8] =  y[h][0] - y[h][4] - y[h][7];
        float t[9];
#pragma unroll
        for (int i = 0; i < 3; ++i)
#pragma unroll
            for (int j = 0; j < 3; ++j) {
                float acc = 0.f;
#pragma unroll
                for (int k = 0; k < 3; ++k)
                    acc += yf[i*3+k] * m[k*3+j] + m[i*3+k] * yf[k*3+j];
                t[i*3+j] = acc;
            }
        float nr = 0.f;
#pragma unroll
        for (int k = 0; k < 9; ++k) { float u = t[k] + 1.0f; nr += u * u; }
        float inv = 1.0f / nr;
#pragma unroll
        for (int k = 0; k < 9; ++k) t[k] *= inv;
        float dm = (t[0] + t[4] + t[8]) * (1.0f / 3.0f);
        yn2[h][0] = dm;
        yn2[h][1] = 0.5f * (t[1] - t[3]);
        yn2[h][2] = 0.5f * (t[2] - t[6]);
        yn2[h][3] = 0.5f * (t[5] - t[7]);
        yn2[h][4] = t[0] - dm;
        yn2[h][5] = 0.5f * (t[1] + t[3]);
        yn2[h][6] = 0.5f * (t[2] + t[6]);
        yn2[h][7] = t[4] - dm;
        yn2[h][8] = 0.5f * (t[5] + t[7]);
    }
    __syncthreads();                                    // (8) comps + WSpre reads done

#pragma unroll
    for (int h = 0; h < 4; ++h) {
        const int c = q + 16 * h;
#pragma unroll
        for (int k = 0; k < 9; ++k) vb[k * 64 + c] = yn2[h][k];
    }
    stage_w(WIpost, wbuf, tid);
    __syncthreads();                                    // (9)

    // ---- post mixing ----
    float z[4][9];
#pragma unroll
    for (int j = 0; j < 4; ++j)
#pragma unroll
        for (int k = 0; k < 9; ++k) z[j][k] = 0.f;

    mix_phase<0, 1>(vb, wbuf, q, z);
    __syncthreads();                                    // (10)
    stage_w(WApost, wbuf, tid);
    __syncthreads();                                    // (11)
    mix_phase<1, 3>(vb, wbuf, q, z);
    __syncthreads();                                    // (12)
    stage_w(WSpost, wbuf, tid);
    __syncthreads();                                    // (13)
    mix_phase<4, 5>(vb, wbuf, q, z);
    __syncthreads();                                    // (14) done reading comps

    // ---- reconstruct, out = Y + Y@Y, stage contiguous per node ----
#pragma unroll
    for (int h = 0; h < 4; ++h) {
        const int o = q + 16 * h;
        float w[9];
        w[0] =  z[h][0] + z[h][4];
        w[1] =  z[h][1] + z[h][5];
        w[2] =  z[h][2] + z[h][6];
        w[3] = -z[h][1] + z[h][5];
        w[4] =  z[h][0] + z[h][7];
        w[5] =  z[h][3] + z[h][8];
        w[6] = -z[h][2] + z[h][6];
        w[7] = -z[h][3] + z[h][8];
        w[8] =  z[h][0] - z[h][4] - z[h][7];
#pragma unroll
        for (int i = 0; i < 3; ++i)
#pragma unroll
            for (int j = 0; j < 3; ++j) {
                float acc = w[i*3+j];
#pragma unroll
                for (int k = 0; k < 3; ++k) acc += w[i*3+k] * w[k*3+j];
                vb[o * 9 + i*3+j] = acc;
            }
    }
    __syncthreads();                                    // (15)
    {
        float4* dst = reinterpret_cast<float4*>(out + (size_t)node0 * 576);
        const float4* srcv = reinterpret_cast<const float4*>(vals);
        for (int i = tid; i < 2304; i += 256) dst[i] = srcv[(i / 144) * VSTR4 + (i % 144)];
    }
}

// ===========================================================================
extern "C" void kernel_launch(void* const* d_in, const int* in_sizes, int n_in,
                              void* d_out, int out_size, void* d_ws, size_t ws_size,
                              hipStream_t stream)
{
    const float* X      = (const float*)d_in[0];
    const float* dist   = (const float*)d_in[1];
    const int*   nb     = (const int*)d_in[2];
    const float* WIpre  = (const float*)d_in[3];
    const float* WApre  = (const float*)d_in[4];
    const float* WSpre  = (const float*)d_in[5];
    const float* WIpost = (const float*)d_in[6];
    const float* WApost = (const float*)d_in[7];
    const float* WSpost = (const float*)d_in[8];
    const float* Wdist  = (const float*)d_in[9];
    const float* bdist  = (const float*)d_in[10];
    float* out = (float*)d_out;

    // workspace layout (floats/ints)
    float* Phi      = (float*)d_ws;                         // 20000*32 f
    float* Env      = Phi + (size_t)NNODES * 32;            // 20000 f
    float* sorted_d = Env + NNODES;                         // 320000 f
    int*   counts   = (int*)(sorted_d + NEDGES);            // 20000 i
    int*   cursor   = counts + NNODES;                      // 20000 i
    int*   base     = cursor + NNODES;                      // 20000 i

    // zero counts+cursor only (contiguous)
    hipMemsetAsync(counts, 0, 2 * (size_t)NNODES * sizeof(int), stream);

    double em5   = std::exp(-5.0);
    double step  = (1.0 - em5) / 31.0;
    double fac   = (2.0 / 32.0) * (1.0 - em5);
    double betad = 1.0 / (fac * fac);

    hist_kernel<<<(NEDGES + 255) / 256, 256, 0, stream>>>(nb, counts);
    scan_kernel<<<1, 1024, 0, stream>>>(counts, base);
    fill_kernel<<<(NEDGES + 255) / 256, 256, 0, stream>>>(dist, nb, base, cursor, sorted_d);
    node_phi_kernel<<<(NNODES + 63) / 64, 64, 0, stream>>>(
        sorted_d, base, counts, Phi, Env, (float)em5, (float)step, (float)betad);
    node_kernel<<<NNODES / 16, 256, 0, stream>>>(
        X, Phi, Env, WIpre, WApre, WSpre, WIpost, WApost, WSpost, Wdist, bdist, out);
}